// Round 1
// baseline (298.079 us; speedup 1.0000x reference)
//
#include <hip/hip_runtime.h>

// LovaszSoftmaxLoss B=8, C=21, H=W=512 — sort-free counting-sort formulation.
// R5: split the fused kernel. Theory: k_fused's v[21][4] (84 VGPRs live) under a
// 128-VGPR cap + 63KB LDS (2 blocks/CU) made it latency/spill-bound at ~255us vs
// a ~80us pipe floor. New structure:
//   A) k_norm: per-pixel L = m + log(sum exp(x-m))  (35 VGPR, streaming, 176MB->8MB)
//   B) k_hist: one block per (b, class, 8K-px chunk); p = exp(x-L); 3KB LDS hist,
//      ~30 VGPR, 8 blocks/CU. L/tgt re-read 21x but 8MB each -> L3-resident.
//   C) k_scan: unchanged 768-bin descending scan, merging 32 partials/row.
// Key = 12 octaves x 6 mantissa bits = 768 bins (bin-center rel err 0.78%).

#define NB     8
#define NC     21
#define NPIX   262144          // 2^18
#define NROWS  (NB * NC)       // 168
#define NBINS  768             // key = (fexp+12)<<6 | mant6 ; fexp in [-12,0]
#define CHUNKS 32              // hist chunks per (b,c) row
#define HCHUNK (NPIX / CHUNKS) // 8192 px per k_hist block

// ---------------- Kernel A: per-pixel log-normalizer ----------------
// 2M threads, 1 px each. L[b,n] = m + ln(sum_c exp(x[b,c,n]-m)); p = exp(x-L).
__global__ __launch_bounds__(256) void k_norm(
    const float* __restrict__ x, float* __restrict__ L) {
  int g = blockIdx.x * 256 + threadIdx.x;        // 0..NB*NPIX, g = b*NPIX + n
  int b = g >> 18;
  const float* xp = x + (size_t)b * (NC - 1) * NPIX + g;  // = &x[b][0][n]
  float v[NC];
  float m = -3.4e38f;
  #pragma unroll
  for (int c = 0; c < NC; ++c) {
    v[c] = xp[(size_t)c * NPIX];
    m = fmaxf(m, v[c]);
  }
  float Z = 0.f;
  #pragma unroll
  for (int c = 0; c < NC; ++c) Z += __expf(v[c] - m);
  L[g] = m + __logf(Z);
}

// ---------------- Kernel B: per-(b,c,chunk) histogram ----------------
// 256 threads, 32 px/thread (8 float4 groups). 3KB LDS hist -> 8 blocks/CU.
// count<=8192 (13b) in high bits, labelsum<=163840 (<2^18) in low 18 bits.
__global__ __launch_bounds__(256) void k_hist(
    const float* __restrict__ x,
    const int* __restrict__ tgt,
    const float* __restrict__ L,
    unsigned* __restrict__ partial) {
  __shared__ unsigned hist[NBINS];               // 3 KB
  int tid = threadIdx.x;
  int bid = blockIdx.x;                          // (b*CHUNKS + ch)*NC + c  (c fastest: L2 reuse of L/tgt)
  int c   = bid % NC;
  int bc  = bid / NC;
  int b   = bc / CHUNKS;
  int ch  = bc - b * CHUNKS;

  for (int i = tid; i < NBINS; i += 256) hist[i] = 0;
  __syncthreads();

  int n0 = ch * HCHUNK;
  const float* xb = x   + (size_t)(b * NC + c) * NPIX + n0;
  const float* Lb = L   + (size_t)b * NPIX + n0;
  const int*   tb = tgt + (size_t)b * NPIX + n0;

  #pragma unroll
  for (int g = 0; g < 8; ++g) {
    int n4 = (g * 256 + tid) * 4;                // coalesced float4
    float4 xv = *(const float4*)(xb + n4);
    float4 lv = *(const float4*)(Lb + n4);
    int4   tv = *(const int4*)(tb + n4);
    float xs[4] = {xv.x, xv.y, xv.z, xv.w};
    float ls[4] = {lv.x, lv.y, lv.z, lv.w};
    int   ts[4] = {tv.x, tv.y, tv.z, tv.w};
    #pragma unroll
    for (int j = 0; j < 4; ++j) {
      float p = __expf(xs[j] - ls[j]);           // softmax prob, p <= 1
      float e = fabsf(((c == ts[j]) ? 1.0f : 0.0f) - p);
      unsigned fb   = __float_as_uint(e);
      int      fexp = (int)(fb >> 23) - 127;
      unsigned key;
      if (fexp < -12) key = 0u;
      else {
        key = (((unsigned)(fexp + 12)) << 6) | ((fb >> 17) & 63u);
        if (key > NBINS - 1) key = NBINS - 1;    // e==1.0 / safety
      }
      atomicAdd(hist + key, (1u << 18) | (unsigned)ts[j]);
    }
  }
  __syncthreads();

  unsigned* op = partial + (size_t)bid * NBINS;
  for (int i = tid; i < NBINS; i += 256) op[i] = hist[i];
}

// ---------------- u64 shuffle helpers ----------------
__device__ inline unsigned long long shfl_up_u64(unsigned long long v, int off) {
  unsigned lo = (unsigned)v, hi = (unsigned)(v >> 32);
  lo = (unsigned)__shfl_up((int)lo, off, 64);
  hi = (unsigned)__shfl_up((int)hi, off, 64);
  return ((unsigned long long)hi << 32) | lo;
}
__device__ inline unsigned long long shfl_down_u64(unsigned long long v, int off) {
  unsigned lo = (unsigned)v, hi = (unsigned)(v >> 32);
  lo = (unsigned)__shfl_down((int)lo, off, 64);
  hi = (unsigned)__shfl_down((int)hi, off, 64);
  return ((unsigned long long)hi << 32) | lo;
}

// ---------------- Scan kernel: merge 32 partials/row + descending scan ----------------
// 168 blocks x 768 threads (12 waves); one thread per bin.
__global__ __launch_bounds__(768) void k_scan(
    const unsigned* __restrict__ partial,
    float* __restrict__ out) {
  int row  = blockIdx.x;                     // 0..167
  int b    = row / NC;
  int c    = row - b * NC;
  int tid  = threadIdx.x;                    // == bin slot
  int lane = tid & 63;
  int wave = tid >> 6;                       // 12 waves

  __shared__ unsigned long long hist0[NBINS];   // 6 KB
  __shared__ unsigned long long wtot[12];
  __shared__ double wred[12];
  __shared__ double sT;

  // merge 32 chunk-partials for (b, c): coalesced 768-wide loads
  {
    const unsigned* pp = partial + ((size_t)(b * CHUNKS) * NC + c) * NBINS + tid;
    unsigned long long cnt = 0, ls = 0;
    #pragma unroll 8
    for (int j = 0; j < CHUNKS; ++j) {
      unsigned v = pp[(size_t)j * NC * NBINS];
      cnt += (v >> 18);
      ls  += (v & 0x3FFFFu);
    }
    hist0[tid] = (cnt << 32) | ls;
  }
  __syncthreads();

  // total labelsum T (exact; fields can't overflow: cnt<=262144, ls<=5.3M)
  unsigned long long tot = hist0[tid];
  #pragma unroll
  for (int off = 32; off > 0; off >>= 1) tot += shfl_down_u64(tot, off);
  if (lane == 0) wtot[wave] = tot;
  __syncthreads();
  if (tid == 0) {
    unsigned long long gsum = 0;
    #pragma unroll
    for (int w = 0; w < 12; ++w) gsum += wtot[w];
    sT = (double)(unsigned)(gsum & 0xffffffffULL);
  }
  __syncthreads();
  double T = sT;
  __syncthreads();

  // single-chunk descending scan over 768 bins
  int bin = (NBINS - 1) - tid;
  unsigned long long v = hist0[bin];

  unsigned long long s = v;                  // intra-wave inclusive scan
  #pragma unroll
  for (int off = 1; off < 64; off <<= 1) {
    unsigned long long u = shfl_up_u64(s, off);
    if (lane >= off) s += u;
  }
  if (lane == 63) wtot[wave] = s;
  __syncthreads();

  unsigned long long woff = 0;
  for (int w = 0; w < wave; ++w) woff += wtot[w];
  unsigned long long excl = s - v + woff;    // strictly-greater prefix

  double acc = 0.0;
  unsigned n = (unsigned)(v >> 32);
  if (n) {
    unsigned sl = (unsigned)(v & 0xffffffffu);
    unsigned cb = (unsigned)(excl >> 32);
    unsigned sb = (unsigned)(excl & 0xffffffffu);
    double Sb = (double)sb + (double)sl;
    double gb = 1.0 - (T - Sb) / (T + (double)(cb + n) - Sb);
    double ga = (cb == 0) ? 0.0
                          : 1.0 - (T - (double)sb) / (T + (double)cb - (double)sb);
    unsigned key = (unsigned)bin;
    unsigned ex  = key >> 6, mant = key & 63u;
    float e = ldexpf(1.0f + ((float)mant + 0.5f) * 0.015625f, (int)ex - 12);
    acc = (double)e * (gb - ga);
  }

  // block reduce acc (12 waves)
  #pragma unroll
  for (int off = 32; off > 0; off >>= 1) acc += __shfl_down(acc, off, 64);
  if (lane == 0) wred[wave] = acc;
  __syncthreads();
  if (tid == 0) {
    double ssum = 0.0;
    #pragma unroll
    for (int w = 0; w < 12; ++w) ssum += wred[w];
    atomicAdd(out, (float)(ssum * (1.0 / (double)NROWS)));
  }
}

extern "C" void kernel_launch(void* const* d_in, const int* in_sizes, int n_in,
                              void* d_out, int out_size, void* d_ws, size_t ws_size,
                              hipStream_t stream) {
  const float* x  = (const float*)d_in[0];   // (B, C, H, W) float32
  const int* tgt  = (const int*)d_in[1];     // (B, H, W) int32
  float* out      = (float*)d_out;
  float* L        = (float*)d_ws;                                   // 8 MB
  unsigned* partial = (unsigned*)((char*)d_ws + (size_t)NB * NPIX * sizeof(float)); // 16.5 MB

  hipMemsetAsync(d_out, 0, sizeof(float), stream);
  k_norm<<<(NB * NPIX) / 256, 256, 0, stream>>>(x, L);
  k_hist<<<NB * CHUNKS * NC, 256, 0, stream>>>(x, tgt, L, partial);
  k_scan<<<NROWS, NBINS, 0, stream>>>(partial, out);
}

// Round 2
// 266.315 us; speedup vs baseline: 1.1193x; 1.1193x over previous
//
#include <hip/hip_runtime.h>

// LovaszSoftmaxLoss B=8, C=21, H=W=512 — sort-free counting-sort formulation.
// loss = sum_i e_i*(g_i - g_{i-1}) over descending-sorted errors; equal-key
// runs contribute e*(g(b)-g(a-1)) independent of tie order, so a histogram
// over quantized keys suffices. Key = 12 octaves x 6 mantissa bits = 768 bins.
//
// R6: revert R5 split (regressed +27us == exactly the +165MB extra traffic at
// 6.1 TB/s -> we are HBM-traffic-bound on top of ~230us fixed harness poison
// fills visible in counters). R4's reg-held fused kernel was ALREADY at its
// traffic roofline (no spill penalty). Only remaining lever: shrink partial
// traffic. 1024 threads x 8192 px/block -> 256 blocks -> partial 16.5 MB
// (was 33 MB), write+read saves ~33 MB ~ 5-6 us.
// Traffic: 176 (x) + 8 (tgt) + 16.5 (partial w) + 16.5 (partial r) = 217 MB.

#define NB     8
#define NC     21
#define NPIX   262144
#define NROWS  (NB * NC)       // 168
#define NBINS  768             // key = (fexp+12)<<6 | mant6 ; fexp in [-12,0]
#define CHUNKS 32              // blocks per batch
#define CHUNK  (NPIX / CHUNKS) // 8192 pixels per block

// ---------------- Fused kernel: softmax -> error -> per-block LDS histograms ----------------
// 1024 threads, 8 px/thread (2 float4 groups). count<=8192 (14b field),
// labelsum<=163840 (<2^18). One block/CU (63KB LDS), 16 waves/CU.
__global__ __launch_bounds__(1024, 1) void k_fused(
    const float* __restrict__ x,
    const int* __restrict__ tgt,
    unsigned* __restrict__ partial) {
  __shared__ unsigned hist[NC * NBINS];      // 63 KB
  int tid = threadIdx.x;
  for (int i = tid; i < NC * NBINS; i += 1024) hist[i] = 0;
  __syncthreads();

  int b     = blockIdx.x >> 5;
  int chunk = blockIdx.x & 31;
  const float* xb = x + (size_t)b * NC * NPIX + (size_t)chunk * CHUNK;
  const int*   tb = tgt + (size_t)b * NPIX + (size_t)chunk * CHUNK;

  #pragma unroll
  for (int g = 0; g < 2; ++g) {
    int n4 = (g * 1024 + tid) * 4;           // 0..8188, coalesced float4

    float v[NC][4];
    float m[4] = {-3.4e38f, -3.4e38f, -3.4e38f, -3.4e38f};
    #pragma unroll
    for (int c = 0; c < NC; ++c) {
      float4 t = *(const float4*)(xb + (size_t)c * NPIX + n4);
      v[c][0] = t.x; v[c][1] = t.y; v[c][2] = t.z; v[c][3] = t.w;
      m[0] = fmaxf(m[0], t.x); m[1] = fmaxf(m[1], t.y);
      m[2] = fmaxf(m[2], t.z); m[3] = fmaxf(m[3], t.w);
    }
    float Z[4] = {0.f, 0.f, 0.f, 0.f};
    #pragma unroll
    for (int c = 0; c < NC; ++c) {
      #pragma unroll
      for (int j = 0; j < 4; ++j) {
        v[c][j] = __expf(v[c][j] - m[j]);
        Z[j] += v[c][j];
      }
    }
    float iZ[4];
    #pragma unroll
    for (int j = 0; j < 4; ++j) iZ[j] = 1.0f / Z[j];

    int4 tv = *(const int4*)(tb + n4);
    int tl[4] = {tv.x, tv.y, tv.z, tv.w};

    #pragma unroll
    for (int c = 0; c < NC; ++c) {
      unsigned* hr = hist + c * NBINS;
      #pragma unroll
      for (int j = 0; j < 4; ++j) {
        float p = v[c][j] * iZ[j];
        float e = fabsf(((c == tl[j]) ? 1.0f : 0.0f) - p);   // e in [0,1]
        unsigned fb   = __float_as_uint(e);
        int      fexp = (int)(fb >> 23) - 127;
        unsigned key;
        if (fexp < -12) key = 0u;
        else {
          key = (((unsigned)(fexp + 12)) << 6) | ((fb >> 17) & 63u);
          if (key > NBINS - 1) key = NBINS - 1;              // e==1.0 / safety
        }
        atomicAdd(hr + key, (1u << 18) | (unsigned)tl[j]);
      }
    }
  }
  __syncthreads();

  unsigned* op = partial + (size_t)blockIdx.x * NC * NBINS;
  for (int i = tid; i < NC * NBINS; i += 1024) op[i] = hist[i];
}

// ---------------- u64 shuffle helpers ----------------
__device__ inline unsigned long long shfl_up_u64(unsigned long long v, int off) {
  unsigned lo = (unsigned)v, hi = (unsigned)(v >> 32);
  lo = (unsigned)__shfl_up((int)lo, off, 64);
  hi = (unsigned)__shfl_up((int)hi, off, 64);
  return ((unsigned long long)hi << 32) | lo;
}
__device__ inline unsigned long long shfl_down_u64(unsigned long long v, int off) {
  unsigned lo = (unsigned)v, hi = (unsigned)(v >> 32);
  lo = (unsigned)__shfl_down((int)lo, off, 64);
  hi = (unsigned)__shfl_down((int)hi, off, 64);
  return ((unsigned long long)hi << 32) | lo;
}

// ---------------- Scan kernel: merge 32 partials/row + descending scan ----------------
// 168 blocks x 768 threads (12 waves); one thread per bin.
__global__ __launch_bounds__(768) void k_scan(
    const unsigned* __restrict__ partial,
    float* __restrict__ out) {
  int row  = blockIdx.x;                     // 0..167
  int b    = row / NC;
  int c    = row - b * NC;
  int tid  = threadIdx.x;                    // == bin slot
  int lane = tid & 63;
  int wave = tid >> 6;                       // 12 waves

  __shared__ unsigned long long hist0[NBINS];   // 6 KB
  __shared__ unsigned long long wtot[12];
  __shared__ double wred[12];
  __shared__ double sT;

  // merge 32 block-partials for (b, c): coalesced 768-wide loads
  {
    const unsigned* pp = partial + ((size_t)(b * CHUNKS) * NC + c) * NBINS + tid;
    unsigned long long cnt = 0, ls = 0;
    #pragma unroll 8
    for (int j = 0; j < CHUNKS; ++j) {
      unsigned v = pp[(size_t)j * NC * NBINS];
      cnt += (v >> 18);
      ls  += (v & 0x3FFFFu);
    }
    hist0[tid] = (cnt << 32) | ls;
  }
  __syncthreads();

  // total labelsum T (exact; fields can't overflow: cnt<=262144, ls<=5.3M)
  unsigned long long tot = hist0[tid];
  #pragma unroll
  for (int off = 32; off > 0; off >>= 1) tot += shfl_down_u64(tot, off);
  if (lane == 0) wtot[wave] = tot;
  __syncthreads();
  if (tid == 0) {
    unsigned long long g = 0;
    #pragma unroll
    for (int w = 0; w < 12; ++w) g += wtot[w];
    sT = (double)(unsigned)(g & 0xffffffffULL);
  }
  __syncthreads();
  double T = sT;
  __syncthreads();

  // single-chunk descending scan over 768 bins
  int bin = (NBINS - 1) - tid;
  unsigned long long v = hist0[bin];

  unsigned long long s = v;                  // intra-wave inclusive scan
  #pragma unroll
  for (int off = 1; off < 64; off <<= 1) {
    unsigned long long u = shfl_up_u64(s, off);
    if (lane >= off) s += u;
  }
  if (lane == 63) wtot[wave] = s;
  __syncthreads();

  unsigned long long woff = 0;
  for (int w = 0; w < wave; ++w) woff += wtot[w];
  unsigned long long excl = s - v + woff;    // strictly-greater prefix

  double acc = 0.0;
  unsigned n = (unsigned)(v >> 32);
  if (n) {
    unsigned sl = (unsigned)(v & 0xffffffffu);
    unsigned cb = (unsigned)(excl >> 32);
    unsigned sb = (unsigned)(excl & 0xffffffffu);
    double Sb = (double)sb + (double)sl;
    double gb = 1.0 - (T - Sb) / (T + (double)(cb + n) - Sb);
    double ga = (cb == 0) ? 0.0
                          : 1.0 - (T - (double)sb) / (T + (double)cb - (double)sb);
    unsigned key = (unsigned)bin;
    unsigned ex  = key >> 6, mant = key & 63u;
    float e = ldexpf(1.0f + ((float)mant + 0.5f) * 0.015625f, (int)ex - 12);
    acc = (double)e * (gb - ga);
  }

  // block reduce acc (12 waves)
  #pragma unroll
  for (int off = 32; off > 0; off >>= 1) acc += __shfl_down(acc, off, 64);
  if (lane == 0) wred[wave] = acc;
  __syncthreads();
  if (tid == 0) {
    double ssum = 0.0;
    #pragma unroll
    for (int w = 0; w < 12; ++w) ssum += wred[w];
    atomicAdd(out, (float)(ssum * (1.0 / (double)NROWS)));
  }
}

extern "C" void kernel_launch(void* const* d_in, const int* in_sizes, int n_in,
                              void* d_out, int out_size, void* d_ws, size_t ws_size,
                              hipStream_t stream) {
  const float* x  = (const float*)d_in[0];   // (B, C, H, W) float32
  const int* tgt  = (const int*)d_in[1];     // (B, H, W) int32
  float* out      = (float*)d_out;
  unsigned* partial = (unsigned*)d_ws;       // 256*21*768*4 = 16.5 MB

  hipMemsetAsync(d_out, 0, sizeof(float), stream);
  k_fused<<<NB * CHUNKS, 1024, 0, stream>>>(x, tgt, partial);
  k_scan<<<NROWS, NBINS, 0, stream>>>(partial, out);
}